// Round 16
// baseline (152.861 us; speedup 1.0000x reference)
//
#include <hip/hip_runtime.h>
#include <hip/hip_bf16.h>

#define N_ROWS 131072
#define DIM 64
#define K_CODES 1024
#define NTILES 64
#define HTILES 32                 // tiles per k-half
#define MARGIN 4e-5f
#define LIST_CAP 65536

typedef short short8 __attribute__((ext_vector_type(8)));
typedef float f32x4 __attribute__((ext_vector_type(4)));

__device__ __forceinline__ unsigned short f2bf(float f) {
    unsigned u = __float_as_uint(f);
    return (unsigned short)((u + 0x7fffu + ((u >> 16) & 1u)) >> 16);  // RNE
}
__device__ __forceinline__ float bf2f(unsigned short h) {
    return __uint_as_float(((unsigned)h) << 16);
}

// np-exact squared-row-sum: elementwise square then pairwise 8-accumulator
__device__ __forceinline__ float np_sq64(const float* __restrict__ v) {
    float xx[DIM];
    #pragma unroll
    for (int d = 0; d < DIM; ++d) xx[d] = v[d] * v[d];
    float r[8];
    #pragma unroll
    for (int j = 0; j < 8; ++j) r[j] = xx[j];
    #pragma unroll
    for (int i = 8; i < DIM; i += 8)
        #pragma unroll
        for (int j = 0; j < 8; ++j) r[j] = r[j] + xx[i + j];
    return ((r[0]+r[1]) + (r[2]+r[3])) + ((r[4]+r[5]) + (r[6]+r[7]));
}

// np-exact einsum dot (verified R3 chain): 4 accs, 16-elem chunks, blocks 12,8,4,0
__device__ __forceinline__ float np_dot64(const float* __restrict__ xv,
                                          const float* __restrict__ ek) {
    float a0 = 0.f, a1 = 0.f, a2 = 0.f, a3 = 0.f;
    #pragma unroll
    for (int c = 0; c < DIM; c += 16)
        #pragma unroll
        for (int b = 12; b >= 0; b -= 4) {
            const int d = c + b;
            a0 = a0 + xv[d+0] * ek[d+0];
            a1 = a1 + xv[d+1] * ek[d+1];
            a2 = a2 + xv[d+2] * ek[d+2];
            a3 = a3 + xv[d+3] * ek[d+3];
        }
    return (a0 + a1) + (a2 + a3);
}

// ws: byte 0: cnt u32, byte 4: loss f32, float idx 4..1027: esq,
//     byte 8192: B panel 256KB, byte 270336: fixup list u32[65536]

__global__ void vq_prep(const float* __restrict__ emb, float* __restrict__ esq,
                        unsigned short* __restrict__ wsB,
                        unsigned int* __restrict__ cnt, float* __restrict__ loss) {
#pragma clang fp contract(off)
    const int t = blockIdx.x * blockDim.x + threadIdx.x;
    if (t == 0) { *cnt = 0u; *loss = 0.f; }
    const int k = t >> 2, c = t & 3;
    if (k >= K_CODES) return;
    const float* e = emb + (size_t)k * DIM;

    if (c == 0) esq[k] = np_sq64(e);

    const int off = (c & 1) * 32, sel = c >> 1;
    unsigned short val[32];
    #pragma unroll
    for (int j = 0; j < 32; ++j) {
        float v = e[off + j];
        unsigned short h = f2bf(v);
        val[j] = sel ? f2bf(v - bf2f(h)) : h;
    }
    const int tile = k >> 4, n = k & 15;
    #pragma unroll
    for (int g = 0; g < 4; ++g) {
        short8 s;
        #pragma unroll
        for (int j = 0; j < 8; ++j) s[j] = (short)val[g*8 + j];
        *reinterpret_cast<short8*>(wsB + ((size_t)((tile*4 + c)*64 + g*16 + n)) * 8) = s;
    }
}

__global__ __launch_bounds__(256, 2) void vq_mfma(const float* __restrict__ x,
        const float* __restrict__ emb, const float* __restrict__ esq,
        const unsigned short* __restrict__ wsB, float* __restrict__ out,
        unsigned int* __restrict__ cnt, unsigned int* __restrict__ list,
        float* __restrict__ loss) {
#pragma clang fp contract(off)
    const int tid = threadIdx.x;
    const int lane = tid & 63;
    const int w = tid >> 6;
    const int rowgrp = w >> 1;          // 0,1: which 64 rows of the block
    const int khalf = w & 1;            // 0,1: which 512 codes
    const int g = lane >> 4, res = lane & 15;
    const int rowbase = blockIdx.x * 128 + rowgrp * 64;   // 64 rows per wave
    const int kb = khalf * HTILES;      // first tile of this wave's k-half

    // A-frags: lane holds row (rowbase + rg*16 + res), k-slots g*8+j
    short8 Ah[4][2], Al[4][2];
    #pragma unroll
    for (int rg = 0; rg < 4; ++rg) {
        const float* xr = x + (size_t)(rowbase + rg*16 + res) * DIM;
        #pragma unroll
        for (int h = 0; h < 2; ++h) {
            float4 v0 = *reinterpret_cast<const float4*>(xr + h*32 + g*8);
            float4 v1 = *reinterpret_cast<const float4*>(xr + h*32 + g*8 + 4);
            float xv[8] = {v0.x, v0.y, v0.z, v0.w, v1.x, v1.y, v1.z, v1.w};
            short8 sh, sl;
            #pragma unroll
            for (int j = 0; j < 8; ++j) {
                unsigned short hb = f2bf(xv[j]);
                sh[j] = (short)hb;
                sl[j] = (short)f2bf(xv[j] - bf2f(hb));
            }
            Ah[rg][h] = sh; Al[rg][h] = sl;
        }
    }

    // float-key top-3 per row-slot: key = proxy with idx injected in the low
    // 10 mantissa bits. Quantization absorbed by MARGIN; tie-direction quirks
    // are always margin-flagged -> exact resolve/fixup covers them.
    float b1[16], b2[16], b3[16];
    const float FINF = __uint_as_float(0x7F800000u);
    #pragma unroll
    for (int s = 0; s < 16; ++s) { b1[s] = FINF; b2[s] = FINF; b3[s] = FINF; }

    auto loadB = [&](short8* Bd, int ct) {
        const unsigned short* bp = wsB + ((size_t)(ct*4)*64 + lane) * 8;
        #pragma unroll
        for (int c = 0; c < 4; ++c)
            Bd[c] = *reinterpret_cast<const short8*>(bp + (size_t)c * 64 * 8);
    };

    // 24 MFMAs, j-outer / rg-inner (4 independent chains round-robin)
    auto MF = [&](f32x4* acc, const short8* B) {
        #pragma unroll
        for (int rg = 0; rg < 4; ++rg) acc[rg] = f32x4{0.f, 0.f, 0.f, 0.f};
        #pragma unroll
        for (int rg = 0; rg < 4; ++rg)
            acc[rg] = __builtin_amdgcn_mfma_f32_16x16x32_bf16(Ah[rg][0], B[0], acc[rg], 0,0,0);
        #pragma unroll
        for (int rg = 0; rg < 4; ++rg)
            acc[rg] = __builtin_amdgcn_mfma_f32_16x16x32_bf16(Ah[rg][1], B[1], acc[rg], 0,0,0);
        #pragma unroll
        for (int rg = 0; rg < 4; ++rg)
            acc[rg] = __builtin_amdgcn_mfma_f32_16x16x32_bf16(Ah[rg][0], B[2], acc[rg], 0,0,0);
        #pragma unroll
        for (int rg = 0; rg < 4; ++rg)
            acc[rg] = __builtin_amdgcn_mfma_f32_16x16x32_bf16(Ah[rg][1], B[3], acc[rg], 0,0,0);
        #pragma unroll
        for (int rg = 0; rg < 4; ++rg)
            acc[rg] = __builtin_amdgcn_mfma_f32_16x16x32_bf16(Al[rg][0], B[0], acc[rg], 0,0,0);
        #pragma unroll
        for (int rg = 0; rg < 4; ++rg)
            acc[rg] = __builtin_amdgcn_mfma_f32_16x16x32_bf16(Al[rg][1], B[1], acc[rg], 0,0,0);
    };

    // 16 key updates: fmaf + and_or(inject idx) + med3f + med3f + minf
    auto KY = [&](const f32x4* acc, float esqv, int ct) {
        const unsigned kcur = (unsigned)(ct*16 + res);
        #pragma unroll
        for (int rg = 0; rg < 4; ++rg) {
            #pragma unroll
            for (int r = 0; r < 4; ++r) {
                float v = fmaf(-2.0f, acc[rg][r], esqv);   // proxy = esq - 2*dot
                float key = __uint_as_float((__float_as_uint(v) & 0xFFFFFC00u) | kcur);
                const int s = rg*4 + r;
                float o1 = b1[s], o2 = b2[s];
                b3[s] = __builtin_amdgcn_fmed3f(key, o2, b3[s]);
                b2[s] = __builtin_amdgcn_fmed3f(key, o1, o2);
                b1[s] = fminf(o1, key);
            }
        }
    };

    // software pipeline over this wave's 32 tiles: loadB(2 ahead) -> MF -> KY(prev)
    short8 B0[4], B1[4];
    f32x4 accA[4], accB[4];
    float e0, e1;

    loadB(B0, kb + 0); e0 = esq[(kb + 0)*16 + res];
    loadB(B1, kb + 1); e1 = esq[(kb + 1)*16 + res];
    MF(accA, B0);                          // tile kb+0
    for (int p = 0; p < 15; ++p) {         // tiles kb+2p+1, kb+2p+2
        loadB(B0, kb + 2*p + 2);
        MF(accB, B1);                      // covers B0 latency
        KY(accA, e0, kb + 2*p);
        e0 = esq[(kb + 2*p + 2)*16 + res];
        loadB(B1, kb + 2*p + 3);
        MF(accA, B0);
        KY(accB, e1, kb + 2*p + 1);
        e1 = esq[(kb + 2*p + 3)*16 + res];
    }
    MF(accB, B1);                          // tile kb+31
    KY(accA, e0, kb + 30);
    KY(accB, e1, kb + 31);

    // top-3 merge across the 16 code-residue lanes (float order-stat network)
    #pragma unroll
    for (int m = 1; m < 16; m <<= 1) {
        #pragma unroll
        for (int s = 0; s < 16; ++s) {
            float oa1 = __shfl_xor(b1[s], m, 64);
            float oa2 = __shfl_xor(b2[s], m, 64);
            float oa3 = __shfl_xor(b3[s], m, 64);
            float m1 = fminf(b1[s], oa1);
            float m2 = fminf(fmaxf(b1[s], oa1), fminf(b2[s], oa2));
            float m3 = fminf(fminf(fmaxf(b1[s], oa2), fmaxf(b2[s], oa1)),
                             fminf(b3[s], oa3));
            b1[s] = m1; b2[s] = m2; b3[s] = m3;
        }
    }

    // per-(row, khalf) top-3 -> LDS
    __shared__ float s_k1[2][128], s_k2[2][128], s_k3[2][128];
    __shared__ int s_idx[128];
    if (res == 0) {
        #pragma unroll
        for (int s = 0; s < 16; ++s) {   // row_local = rowgrp*64 + rg*16 + g*4 + r
            const int rl = rowgrp*64 + (s >> 2)*16 + g*4 + (s & 3);
            s_k1[khalf][rl] = b1[s]; s_k2[khalf][rl] = b2[s]; s_k3[khalf][rl] = b3[s];
        }
    }
    __syncthreads();

    // resolve pass: 1 thread per row (tid<128). Merge the two k-halves with the
    // same order-stat network, then: outright winner / pair-tie np-exact
    // compare / triple-tie -> fixup.
    if (tid < 128) {
        const int row = blockIdx.x * 128 + tid;
        float a1 = s_k1[0][tid], a2 = s_k2[0][tid], a3 = s_k3[0][tid];
        float c1 = s_k1[1][tid], c2 = s_k2[1][tid], c3 = s_k3[1][tid];
        float k1 = fminf(a1, c1);
        float k2 = fminf(fmaxf(a1, c1), fminf(a2, c2));
        float k3 = fminf(fminf(fmaxf(a1, c2), fmaxf(a2, c1)), fminf(a3, c3));
        unsigned u1 = __float_as_uint(k1);
        unsigned u2 = __float_as_uint(k2);
        unsigned u3 = __float_as_uint(k3);
        float f1 = __uint_as_float(u1 & 0xFFFFFC00u);
        float f2 = __uint_as_float(u2 & 0xFFFFFC00u);
        float f3 = __uint_as_float(u3 & 0xFFFFFC00u);
        int idx;
        if (f3 - f1 < MARGIN) {
            unsigned slot = atomicAdd(cnt, 1u);
            if (slot < LIST_CAP) list[slot] = (unsigned)row;
            idx = -1;                              // fixup owns this row
        } else if (f2 - f1 < MARGIN) {
            const int ia = (int)(u1 & 0x3FFu), ib = (int)(u2 & 0x3FFu);
            float xv[DIM];
            const float4* xp = reinterpret_cast<const float4*>(x + (size_t)row * DIM);
            #pragma unroll
            for (int q = 0; q < 16; ++q) {
                float4 v = xp[q];
                xv[4*q+0] = v.x; xv[4*q+1] = v.y; xv[4*q+2] = v.z; xv[4*q+3] = v.w;
            }
            float xsq = np_sq64(xv);
            float ta = xsq + esq[ia];
            float da = ta - 2.0f * np_dot64(xv, emb + (size_t)ia * DIM);
            float tb = xsq + esq[ib];
            float db = tb - 2.0f * np_dot64(xv, emb + (size_t)ib * DIM);
            // np.argmin first-min semantics
            idx = (da < db) ? ia : ((db < da) ? ib : (ia < ib ? ia : ib));
        } else {
            idx = (int)(u1 & 0x3FFu);
        }
        s_idx[tid] = idx;
    }
    __syncthreads();

    // writeout: 2 threads per row (32 dims each), 128B-stride coalesced
    float lsum = 0.f;
    {
        const int rl = tid >> 1, half = tid & 1;
        const int row = blockIdx.x * 128 + rl;
        const int idx = s_idx[rl];
        if (idx >= 0) {
            const float* xr = x + (size_t)row * DIM + half*32;
            const float* qr = emb + (size_t)idx * DIM + half*32;
            float* orow = out + (size_t)row * DIM + half*32;
            #pragma unroll
            for (int i = 0; i < 8; ++i) {
                float4 xv = reinterpret_cast<const float4*>(xr)[i];
                float4 qv = reinterpret_cast<const float4*>(qr)[i];
                float df0 = qv.x - xv.x, df1 = qv.y - xv.y;
                float df2 = qv.z - xv.z, df3 = qv.w - xv.w;
                lsum = fmaf(df0, df0, lsum); lsum = fmaf(df1, df1, lsum);
                lsum = fmaf(df2, df2, lsum); lsum = fmaf(df3, df3, lsum);
                float4 o = {xv.x + df0, xv.y + df1, xv.z + df2, xv.w + df3};
                reinterpret_cast<float4*>(orow)[i] = o;
            }
            if (half == 0) out[(size_t)N_ROWS * DIM + row] = (float)idx;
        }
    }
    #pragma unroll
    for (int off = 32; off > 0; off >>= 1) lsum += __shfl_down(lsum, off, 64);
    if (lane == 0) atomicAdd(loss, lsum);
}

// full np-exact rescan, only for triple-tie rows (rare)
__global__ void vq_fixup(const float* __restrict__ x, const float* __restrict__ emb,
                         const float* __restrict__ esq,
                         const unsigned int* __restrict__ cnt,
                         const unsigned int* __restrict__ list,
                         float* __restrict__ out, float* __restrict__ loss) {
#pragma clang fp contract(off)
    const int lane = threadIdx.x & 63;
    const int wid = (blockIdx.x * blockDim.x + threadIdx.x) >> 6;
    const int nw = (256 * 256) >> 6;
    unsigned count = *cnt;
    if (count > LIST_CAP) count = LIST_CAP;
    for (unsigned i = wid; i < count; i += nw) {
        const int row = (int)list[i];
        float xv[DIM];
        const float4* xp = reinterpret_cast<const float4*>(x + (size_t)row * DIM);
        #pragma unroll
        for (int q = 0; q < 16; ++q) {
            float4 v = xp[q];
            xv[4*q+0] = v.x; xv[4*q+1] = v.y; xv[4*q+2] = v.z; xv[4*q+3] = v.w;
        }
        float xsq = np_sq64(xv);
        float best = INFINITY; int bidx = 0x7fffffff;
        for (int t = 0; t < K_CODES / 64; ++t) {
            const int k = lane + t * 64;   // ascending per lane
            float dot = np_dot64(xv, emb + (size_t)k * DIM);
            float tt = xsq + esq[k];
            float dist = tt - 2.0f * dot;
            if (dist < best) { best = dist; bidx = k; }
        }
        #pragma unroll
        for (int m = 1; m < 64; m <<= 1) {   // lexicographic (dist, idx) min
            float ob = __shfl_xor(best, m, 64);
            int   oi = __shfl_xor(bidx, m, 64);
            if (ob < best || (ob == best && oi < bidx)) { best = ob; bidx = oi; }
        }
        const float xd = x[(size_t)row * DIM + lane];
        const float qd = emb[(size_t)bidx * DIM + lane];
        const float df = qd - xd;
        out[(size_t)row * DIM + lane] = xd + df;
        if (lane == 0) out[(size_t)N_ROWS * DIM + row] = (float)bidx;
        float l2 = df * df;
        #pragma unroll
        for (int off = 32; off > 0; off >>= 1) l2 += __shfl_down(l2, off, 64);
        if (lane == 0) atomicAdd(loss, l2);
    }
}

__global__ void vq_final(const float* __restrict__ loss_acc, float* __restrict__ out_loss) {
    if (threadIdx.x == 0 && blockIdx.x == 0)
        out_loss[0] = loss_acc[0] / (float)((size_t)N_ROWS * DIM);
}

extern "C" void kernel_launch(void* const* d_in, const int* in_sizes, int n_in,
                              void* d_out, int out_size, void* d_ws, size_t ws_size,
                              hipStream_t stream) {
    const float* x   = (const float*)d_in[0];
    const float* emb = (const float*)d_in[1];
    float* out = (float*)d_out;

    unsigned int* cnt  = (unsigned int*)d_ws;
    float* loss        = (float*)d_ws + 1;
    float* esq         = (float*)d_ws + 4;
    unsigned short* wsB = (unsigned short*)((char*)d_ws + 8192);
    unsigned int* list = (unsigned int*)((char*)d_ws + 270336);

    vq_prep<<<dim3(16), dim3(256), 0, stream>>>(emb, esq, wsB, cnt, loss);
    vq_mfma<<<dim3(N_ROWS / 128), dim3(256), 0, stream>>>(x, emb, esq, wsB, out,
                                                          cnt, list, loss);
    vq_fixup<<<dim3(256), dim3(256), 0, stream>>>(x, emb, esq, cnt, list, out, loss);
    vq_final<<<dim3(1), dim3(1), 0, stream>>>(loss, out + (size_t)N_ROWS * DIM + N_ROWS);
}

// Round 18
// 134.223 us; speedup vs baseline: 1.1389x; 1.1389x over previous
//
#include <hip/hip_runtime.h>
#include <hip/hip_bf16.h>

#define N_ROWS 131072
#define DIM 64
#define K_CODES 1024
#define NTILES 64
#define MARGIN 4e-5f
#define LIST_CAP 65536

typedef short short8 __attribute__((ext_vector_type(8)));
typedef float f32x4 __attribute__((ext_vector_type(4)));

__device__ __forceinline__ unsigned short f2bf(float f) {
    unsigned u = __float_as_uint(f);
    return (unsigned short)((u + 0x7fffu + ((u >> 16) & 1u)) >> 16);  // RNE
}
__device__ __forceinline__ float bf2f(unsigned short h) {
    return __uint_as_float(((unsigned)h) << 16);
}

// np-exact squared-row-sum: elementwise square then pairwise 8-accumulator
__device__ __forceinline__ float np_sq64(const float* __restrict__ v) {
    float xx[DIM];
    #pragma unroll
    for (int d = 0; d < DIM; ++d) xx[d] = v[d] * v[d];
    float r[8];
    #pragma unroll
    for (int j = 0; j < 8; ++j) r[j] = xx[j];
    #pragma unroll
    for (int i = 8; i < DIM; i += 8)
        #pragma unroll
        for (int j = 0; j < 8; ++j) r[j] = r[j] + xx[i + j];
    return ((r[0]+r[1]) + (r[2]+r[3])) + ((r[4]+r[5]) + (r[6]+r[7]));
}

// np-exact einsum dot (verified R3 chain): 4 accs, 16-elem chunks, blocks 12,8,4,0
__device__ __forceinline__ float np_dot64(const float* __restrict__ xv,
                                          const float* __restrict__ ek) {
    float a0 = 0.f, a1 = 0.f, a2 = 0.f, a3 = 0.f;
    #pragma unroll
    for (int c = 0; c < DIM; c += 16)
        #pragma unroll
        for (int b = 12; b >= 0; b -= 4) {
            const int d = c + b;
            a0 = a0 + xv[d+0] * ek[d+0];
            a1 = a1 + xv[d+1] * ek[d+1];
            a2 = a2 + xv[d+2] * ek[d+2];
            a3 = a3 + xv[d+3] * ek[d+3];
        }
    return (a0 + a1) + (a2 + a3);
}

// ws: byte 0: cnt u32, byte 4: loss f32, float idx 4..1027: esq,
//     byte 8192: B panel 256KB, byte 270336: fixup list u32[65536]

__global__ void vq_prep(const float* __restrict__ emb, float* __restrict__ esq,
                        unsigned short* __restrict__ wsB,
                        unsigned int* __restrict__ cnt, float* __restrict__ loss) {
#pragma clang fp contract(off)
    const int t = blockIdx.x * blockDim.x + threadIdx.x;
    if (t == 0) { *cnt = 0u; *loss = 0.f; }
    const int k = t >> 2, c = t & 3;
    if (k >= K_CODES) return;
    const float* e = emb + (size_t)k * DIM;

    if (c == 0) esq[k] = np_sq64(e);

    const int off = (c & 1) * 32, sel = c >> 1;
    unsigned short val[32];
    #pragma unroll
    for (int j = 0; j < 32; ++j) {
        float v = e[off + j];
        unsigned short h = f2bf(v);
        val[j] = sel ? f2bf(v - bf2f(h)) : h;
    }
    const int tile = k >> 4, n = k & 15;
    #pragma unroll
    for (int g = 0; g < 4; ++g) {
        short8 s;
        #pragma unroll
        for (int j = 0; j < 8; ++j) s[j] = (short)val[g*8 + j];
        *reinterpret_cast<short8*>(wsB + ((size_t)((tile*4 + c)*64 + g*16 + n)) * 8) = s;
    }
}

__global__ __launch_bounds__(256, 2) void vq_mfma(const float* __restrict__ x,
        const float* __restrict__ emb, const float* __restrict__ esq,
        const unsigned short* __restrict__ wsB, float* __restrict__ out,
        unsigned int* __restrict__ cnt, unsigned int* __restrict__ list,
        float* __restrict__ loss) {
#pragma clang fp contract(off)
    const int tid = threadIdx.x;
    const int lane = tid & 63;
    const int w = tid >> 6;
    const int g = lane >> 4, res = lane & 15;
    const int rowbase = blockIdx.x * 256 + w * 64;   // 64 rows per wave (4 rgs)

    auto loadB = [&](short8* Bd, int ct) {
        const unsigned short* bp = wsB + ((size_t)(ct*4)*64 + lane) * 8;
        #pragma unroll
        for (int c = 0; c < 4; ++c)
            Bd[c] = *reinterpret_cast<const short8*>(bp + (size_t)c * 64 * 8);
    };

    // 4-deep B prefetch ring (distance ~3 tiles); issued before A-build so the
    // first tiles' latency hides under the A-frag VALU work.
    short8 B0[4], B1[4], B2[4], B3[4];
    loadB(B0, 0); loadB(B1, 1); loadB(B2, 2); loadB(B3, 3);
    float e0 = esq[res], e1 = esq[16 + res];

    // A-frags: lane holds row (rowbase + rg*16 + res), k-slots g*8+j
    short8 Ah[4][2], Al[4][2];
    #pragma unroll
    for (int rg = 0; rg < 4; ++rg) {
        const float* xr = x + (size_t)(rowbase + rg*16 + res) * DIM;
        #pragma unroll
        for (int h = 0; h < 2; ++h) {
            float4 v0 = *reinterpret_cast<const float4*>(xr + h*32 + g*8);
            float4 v1 = *reinterpret_cast<const float4*>(xr + h*32 + g*8 + 4);
            float xv[8] = {v0.x, v0.y, v0.z, v0.w, v1.x, v1.y, v1.z, v1.w};
            short8 sh, sl;
            #pragma unroll
            for (int j = 0; j < 8; ++j) {
                unsigned short hb = f2bf(xv[j]);
                sh[j] = (short)hb;
                sl[j] = (short)f2bf(xv[j] - bf2f(hb));
            }
            Ah[rg][h] = sh; Al[rg][h] = sl;
        }
    }

    // float-key top-3 per row-slot: key = proxy with idx in low 10 mantissa
    // bits. Quantization absorbed by MARGIN; tie-direction quirks always
    // margin-flagged -> exact resolve/fixup covers them.
    float b1[16], b2[16], b3[16];
    const float FINF = __uint_as_float(0x7F800000u);
    #pragma unroll
    for (int s = 0; s < 16; ++s) { b1[s] = FINF; b2[s] = FINF; b3[s] = FINF; }

    // 24 MFMAs, j-outer / rg-inner; setprio(1) keeps the matrix pipe favored
    // while the co-resident wave is in its VALU (KY) phase.
    auto MF = [&](f32x4* acc, const short8* B) {
        __builtin_amdgcn_s_setprio(1);
        #pragma unroll
        for (int rg = 0; rg < 4; ++rg) acc[rg] = f32x4{0.f, 0.f, 0.f, 0.f};
        #pragma unroll
        for (int rg = 0; rg < 4; ++rg)
            acc[rg] = __builtin_amdgcn_mfma_f32_16x16x32_bf16(Ah[rg][0], B[0], acc[rg], 0,0,0);
        #pragma unroll
        for (int rg = 0; rg < 4; ++rg)
            acc[rg] = __builtin_amdgcn_mfma_f32_16x16x32_bf16(Ah[rg][1], B[1], acc[rg], 0,0,0);
        #pragma unroll
        for (int rg = 0; rg < 4; ++rg)
            acc[rg] = __builtin_amdgcn_mfma_f32_16x16x32_bf16(Ah[rg][0], B[2], acc[rg], 0,0,0);
        #pragma unroll
        for (int rg = 0; rg < 4; ++rg)
            acc[rg] = __builtin_amdgcn_mfma_f32_16x16x32_bf16(Ah[rg][1], B[3], acc[rg], 0,0,0);
        #pragma unroll
        for (int rg = 0; rg < 4; ++rg)
            acc[rg] = __builtin_amdgcn_mfma_f32_16x16x32_bf16(Al[rg][0], B[0], acc[rg], 0,0,0);
        #pragma unroll
        for (int rg = 0; rg < 4; ++rg)
            acc[rg] = __builtin_amdgcn_mfma_f32_16x16x32_bf16(Al[rg][1], B[1], acc[rg], 0,0,0);
        __builtin_amdgcn_s_setprio(0);
    };

    // 16 key updates: fmaf + and_or(inject idx) + med3f + med3f + minf
    auto KY = [&](const f32x4* acc, float esqv, int ct) {
        const unsigned kcur = (unsigned)(ct*16 + res);
        #pragma unroll
        for (int rg = 0; rg < 4; ++rg) {
            #pragma unroll
            for (int r = 0; r < 4; ++r) {
                float v = fmaf(-2.0f, acc[rg][r], esqv);   // proxy = esq - 2*dot
                float key = __uint_as_float((__float_as_uint(v) & 0xFFFFFC00u) | kcur);
                const int s = rg*4 + r;
                float o1 = b1[s], o2 = b2[s];
                b3[s] = __builtin_amdgcn_fmed3f(key, o2, b3[s]);
                b2[s] = __builtin_amdgcn_fmed3f(key, o1, o2);
                b1[s] = fminf(o1, key);
            }
        }
    };

    f32x4 accA[4], accB[4];
    MF(accA, B0);                        // tile 0
    for (int p = 0; p < 15; ++p) {       // tiles 4p+1 .. 4p+4
        const int t = 4 * p;
        loadB(B0, t + 4);
        MF(accB, B1);                    // t+1
        KY(accA, e0, t);      e0 = esq[(t + 2) * 16 + res];
        loadB(B1, t + 5);
        MF(accA, B2);                    // t+2
        KY(accB, e1, t + 1);  e1 = esq[(t + 3) * 16 + res];
        loadB(B2, t + 6);
        MF(accB, B3);                    // t+3
        KY(accA, e0, t + 2);  e0 = esq[(t + 4) * 16 + res];
        loadB(B3, t + 7);
        MF(accA, B0);                    // t+4 (B0 loaded at top of this iter)
        KY(accB, e1, t + 3);  e1 = esq[(t + 5) * 16 + res];
    }
    // epilogue: tiles 61..63 (B1,B2,B3 hold them; e0=esq[60], e1=esq[61])
    MF(accB, B1);                        // 61
    KY(accA, e0, 60);  e0 = esq[62 * 16 + res];
    MF(accA, B2);                        // 62
    KY(accB, e1, 61);  e1 = esq[63 * 16 + res];
    MF(accB, B3);                        // 63
    KY(accA, e0, 62);
    KY(accB, e1, 63);

    // top-3 merge across the 16 code-residue lanes (float order-stat network)
    #pragma unroll
    for (int m = 1; m < 16; m <<= 1) {
        #pragma unroll
        for (int s = 0; s < 16; ++s) {
            float oa1 = __shfl_xor(b1[s], m, 64);
            float oa2 = __shfl_xor(b2[s], m, 64);
            float oa3 = __shfl_xor(b3[s], m, 64);
            float m1 = fminf(b1[s], oa1);
            float m2 = fminf(fmaxf(b1[s], oa1), fminf(b2[s], oa2));
            float m3 = fminf(fminf(fmaxf(b1[s], oa2), fmaxf(b2[s], oa1)),
                             fminf(b3[s], oa3));
            b1[s] = m1; b2[s] = m2; b3[s] = m3;
        }
    }

    __shared__ float s_k1[256], s_k2[256], s_k3[256];
    __shared__ int s_idx[256];
    if (res == 0) {
        #pragma unroll
        for (int s = 0; s < 16; ++s) {   // row_local = w*64 + rg*16 + g*4 + r
            const int rl = w*64 + (s >> 2)*16 + g*4 + (s & 3);
            s_k1[rl] = b1[s]; s_k2[rl] = b2[s]; s_k3[rl] = b3[s];
        }
    }
    __syncthreads();

    // resolve pass: 1 thread per row. Common: outright winner. Pair-tie:
    // np-exact compare of the two candidates. Triple-tie: defer to fixup.
    {
        const int row = blockIdx.x * 256 + tid;
        unsigned u1 = __float_as_uint(s_k1[tid]);
        unsigned u2 = __float_as_uint(s_k2[tid]);
        unsigned u3 = __float_as_uint(s_k3[tid]);
        float f1 = __uint_as_float(u1 & 0xFFFFFC00u);
        float f2 = __uint_as_float(u2 & 0xFFFFFC00u);
        float f3 = __uint_as_float(u3 & 0xFFFFFC00u);
        int idx;
        if (f3 - f1 < MARGIN) {
            unsigned slot = atomicAdd(cnt, 1u);
            if (slot < LIST_CAP) list[slot] = (unsigned)row;
            idx = -1;                              // fixup owns this row
        } else if (f2 - f1 < MARGIN) {
            const int ia = (int)(u1 & 0x3FFu), ib = (int)(u2 & 0x3FFu);
            float xv[DIM];
            const float4* xp = reinterpret_cast<const float4*>(x + (size_t)row * DIM);
            #pragma unroll
            for (int q = 0; q < 16; ++q) {
                float4 v = xp[q];
                xv[4*q+0] = v.x; xv[4*q+1] = v.y; xv[4*q+2] = v.z; xv[4*q+3] = v.w;
            }
            float xsq = np_sq64(xv);
            float ta = xsq + esq[ia];
            float da = ta - 2.0f * np_dot64(xv, emb + (size_t)ia * DIM);
            float tb = xsq + esq[ib];
            float db = tb - 2.0f * np_dot64(xv, emb + (size_t)ib * DIM);
            // np.argmin first-min semantics
            idx = (da < db) ? ia : ((db < da) ? ib : (ia < ib ? ia : ib));
        } else {
            idx = (int)(u1 & 0x3FFu);
        }
        s_idx[tid] = idx;
    }
    __syncthreads();

    // writeout: 2 threads per row (32 dims each), 2 passes, nontemporal stores
    // via ext_vector f32x4 (builtin rejects HIP_vector_type float4).
    float lsum = 0.f;
    #pragma unroll
    for (int pass = 0; pass < 2; ++pass) {
        const int rl = (tid >> 1) + pass * 128, half = tid & 1;
        const int row = blockIdx.x * 256 + rl;
        const int idx = s_idx[rl];
        if (idx >= 0) {
            const float* xr = x + (size_t)row * DIM + half*32;
            const float* qr = emb + (size_t)idx * DIM + half*32;
            float* orow = out + (size_t)row * DIM + half*32;
            #pragma unroll
            for (int i = 0; i < 8; ++i) {
                float4 xv = reinterpret_cast<const float4*>(xr)[i];
                float4 qv = reinterpret_cast<const float4*>(qr)[i];
                float df0 = qv.x - xv.x, df1 = qv.y - xv.y;
                float df2 = qv.z - xv.z, df3 = qv.w - xv.w;
                lsum = fmaf(df0, df0, lsum); lsum = fmaf(df1, df1, lsum);
                lsum = fmaf(df2, df2, lsum); lsum = fmaf(df3, df3, lsum);
                f32x4 o = {xv.x + df0, xv.y + df1, xv.z + df2, xv.w + df3};
                __builtin_nontemporal_store(o, reinterpret_cast<f32x4*>(orow) + i);
            }
            if (half == 0)
                __builtin_nontemporal_store((float)idx, &out[(size_t)N_ROWS * DIM + row]);
        }
    }
    #pragma unroll
    for (int off = 32; off > 0; off >>= 1) lsum += __shfl_down(lsum, off, 64);
    if (lane == 0) atomicAdd(loss, lsum);
}

// full np-exact rescan, only for triple-tie rows (rare)
__global__ void vq_fixup(const float* __restrict__ x, const float* __restrict__ emb,
                         const float* __restrict__ esq,
                         const unsigned int* __restrict__ cnt,
                         const unsigned int* __restrict__ list,
                         float* __restrict__ out, float* __restrict__ loss) {
#pragma clang fp contract(off)
    const int lane = threadIdx.x & 63;
    const int wid = (blockIdx.x * blockDim.x + threadIdx.x) >> 6;
    const int nw = (256 * 256) >> 6;
    unsigned count = *cnt;
    if (count > LIST_CAP) count = LIST_CAP;
    for (unsigned i = wid; i < count; i += nw) {
        const int row = (int)list[i];
        float xv[DIM];
        const float4* xp = reinterpret_cast<const float4*>(x + (size_t)row * DIM);
        #pragma unroll
        for (int q = 0; q < 16; ++q) {
            float4 v = xp[q];
            xv[4*q+0] = v.x; xv[4*q+1] = v.y; xv[4*q+2] = v.z; xv[4*q+3] = v.w;
        }
        float xsq = np_sq64(xv);
        float best = INFINITY; int bidx = 0x7fffffff;
        for (int t = 0; t < K_CODES / 64; ++t) {
            const int k = lane + t * 64;   // ascending per lane
            float dot = np_dot64(xv, emb + (size_t)k * DIM);
            float tt = xsq + esq[k];
            float dist = tt - 2.0f * dot;
            if (dist < best) { best = dist; bidx = k; }
        }
        #pragma unroll
        for (int m = 1; m < 64; m <<= 1) {   // lexicographic (dist, idx) min
            float ob = __shfl_xor(best, m, 64);
            int   oi = __shfl_xor(bidx, m, 64);
            if (ob < best || (ob == best && oi < bidx)) { best = ob; bidx = oi; }
        }
        const float xd = x[(size_t)row * DIM + lane];
        const float qd = emb[(size_t)bidx * DIM + lane];
        const float df = qd - xd;
        out[(size_t)row * DIM + lane] = xd + df;
        if (lane == 0) out[(size_t)N_ROWS * DIM + row] = (float)bidx;
        float l2 = df * df;
        #pragma unroll
        for (int off = 32; off > 0; off >>= 1) l2 += __shfl_down(l2, off, 64);
        if (lane == 0) atomicAdd(loss, l2);
    }
}

__global__ void vq_final(const float* __restrict__ loss_acc, float* __restrict__ out_loss) {
    if (threadIdx.x == 0 && blockIdx.x == 0)
        out_loss[0] = loss_acc[0] / (float)((size_t)N_ROWS * DIM);
}

extern "C" void kernel_launch(void* const* d_in, const int* in_sizes, int n_in,
                              void* d_out, int out_size, void* d_ws, size_t ws_size,
                              hipStream_t stream) {
    const float* x   = (const float*)d_in[0];
    const float* emb = (const float*)d_in[1];
    float* out = (float*)d_out;

    unsigned int* cnt  = (unsigned int*)d_ws;
    float* loss        = (float*)d_ws + 1;
    float* esq         = (float*)d_ws + 4;
    unsigned short* wsB = (unsigned short*)((char*)d_ws + 8192);
    unsigned int* list = (unsigned int*)((char*)d_ws + 270336);

    vq_prep<<<dim3(16), dim3(256), 0, stream>>>(emb, esq, wsB, cnt, loss);
    vq_mfma<<<dim3(N_ROWS / 256), dim3(256), 0, stream>>>(x, emb, esq, wsB, out,
                                                          cnt, list, loss);
    vq_fixup<<<dim3(256), dim3(256), 0, stream>>>(x, emb, esq, cnt, list, out, loss);
    vq_final<<<dim3(1), dim3(1), 0, stream>>>(loss, out + (size_t)N_ROWS * DIM + N_ROWS);
}

// Round 19
// 129.784 us; speedup vs baseline: 1.1778x; 1.0342x over previous
//
#include <hip/hip_runtime.h>
#include <hip/hip_bf16.h>

#define N_ROWS 131072
#define DIM 64
#define K_CODES 1024
#define NTILES 64
#define MARGIN 4e-5f
#define LIST_CAP 65536

typedef short short8 __attribute__((ext_vector_type(8)));
typedef float f32x4 __attribute__((ext_vector_type(4)));

__device__ __forceinline__ unsigned short f2bf(float f) {
    unsigned u = __float_as_uint(f);
    return (unsigned short)((u + 0x7fffu + ((u >> 16) & 1u)) >> 16);  // RNE
}
__device__ __forceinline__ float bf2f(unsigned short h) {
    return __uint_as_float(((unsigned)h) << 16);
}

// np-exact squared-row-sum: elementwise square then pairwise 8-accumulator
__device__ __forceinline__ float np_sq64(const float* __restrict__ v) {
    float xx[DIM];
    #pragma unroll
    for (int d = 0; d < DIM; ++d) xx[d] = v[d] * v[d];
    float r[8];
    #pragma unroll
    for (int j = 0; j < 8; ++j) r[j] = xx[j];
    #pragma unroll
    for (int i = 8; i < DIM; i += 8)
        #pragma unroll
        for (int j = 0; j < 8; ++j) r[j] = r[j] + xx[i + j];
    return ((r[0]+r[1]) + (r[2]+r[3])) + ((r[4]+r[5]) + (r[6]+r[7]));
}

// np-exact einsum dot (verified R3 chain): 4 accs, 16-elem chunks, blocks 12,8,4,0
__device__ __forceinline__ float np_dot64(const float* __restrict__ xv,
                                          const float* __restrict__ ek) {
    float a0 = 0.f, a1 = 0.f, a2 = 0.f, a3 = 0.f;
    #pragma unroll
    for (int c = 0; c < DIM; c += 16)
        #pragma unroll
        for (int b = 12; b >= 0; b -= 4) {
            const int d = c + b;
            a0 = a0 + xv[d+0] * ek[d+0];
            a1 = a1 + xv[d+1] * ek[d+1];
            a2 = a2 + xv[d+2] * ek[d+2];
            a3 = a3 + xv[d+3] * ek[d+3];
        }
    return (a0 + a1) + (a2 + a3);
}

// ws: byte 0: cnt u32, byte 4: loss f32, float idx 4..1027: esq,
//     byte 8192: B panel 256KB, byte 270336: fixup list u32[65536]

__global__ void vq_prep(const float* __restrict__ emb, float* __restrict__ esq,
                        unsigned short* __restrict__ wsB,
                        unsigned int* __restrict__ cnt, float* __restrict__ loss) {
#pragma clang fp contract(off)
    const int t = blockIdx.x * blockDim.x + threadIdx.x;   // 64 blocks x 64 thr
    if (t == 0) { *cnt = 0u; *loss = 0.f; }
    const int k = t >> 2, c = t & 3;
    if (k >= K_CODES) return;
    const float* e = emb + (size_t)k * DIM;

    if (c == 0) esq[k] = np_sq64(e);

    const int off = (c & 1) * 32, sel = c >> 1;
    unsigned short val[32];
    #pragma unroll
    for (int j = 0; j < 32; ++j) {
        float v = e[off + j];
        unsigned short h = f2bf(v);
        val[j] = sel ? f2bf(v - bf2f(h)) : h;
    }
    const int tile = k >> 4, n = k & 15;
    #pragma unroll
    for (int g = 0; g < 4; ++g) {
        short8 s;
        #pragma unroll
        for (int j = 0; j < 8; ++j) s[j] = (short)val[g*8 + j];
        *reinterpret_cast<short8*>(wsB + ((size_t)((tile*4 + c)*64 + g*16 + n)) * 8) = s;
    }
}

__global__ __launch_bounds__(256, 2) void vq_mfma(const float* __restrict__ x,
        const float* __restrict__ emb, const float* __restrict__ esq,
        const unsigned short* __restrict__ wsB, float* __restrict__ out,
        unsigned int* __restrict__ cnt, unsigned int* __restrict__ list,
        float* __restrict__ loss) {
#pragma clang fp contract(off)
    const int tid = threadIdx.x;
    const int lane = tid & 63;
    const int w = tid >> 6;
    const int g = lane >> 4, res = lane & 15;
    const int rowbase = blockIdx.x * 256 + w * 64;   // 64 rows per wave (4 rgs)

    auto loadB = [&](short8* Bd, int ct) {
        const unsigned short* bp = wsB + ((size_t)(ct*4)*64 + lane) * 8;
        #pragma unroll
        for (int c = 0; c < 4; ++c)
            Bd[c] = *reinterpret_cast<const short8*>(bp + (size_t)c * 64 * 8);
    };

    // B prefetch ring, issued before A-build (first tiles' latency hides there)
    short8 B0[4], B1[4], B2[4], B3[4];
    loadB(B0, 0); loadB(B1, 1); loadB(B2, 2); loadB(B3, 3);
    float e0 = esq[res], e1 = esq[16 + res];

    // A-frags: lane holds row (rowbase + rg*16 + res), k-slots g*8+j
    short8 Ah[4][2], Al[4][2];
    #pragma unroll
    for (int rg = 0; rg < 4; ++rg) {
        const float* xr = x + (size_t)(rowbase + rg*16 + res) * DIM;
        #pragma unroll
        for (int h = 0; h < 2; ++h) {
            float4 v0 = *reinterpret_cast<const float4*>(xr + h*32 + g*8);
            float4 v1 = *reinterpret_cast<const float4*>(xr + h*32 + g*8 + 4);
            float xv[8] = {v0.x, v0.y, v0.z, v0.w, v1.x, v1.y, v1.z, v1.w};
            short8 sh, sl;
            #pragma unroll
            for (int j = 0; j < 8; ++j) {
                unsigned short hb = f2bf(xv[j]);
                sh[j] = (short)hb;
                sl[j] = (short)f2bf(xv[j] - bf2f(hb));
            }
            Ah[rg][h] = sh; Al[rg][h] = sl;
        }
    }

    // float-key top-4 per row-slot: key = proxy with idx in low 10 mantissa
    // bits. b4 exists only to gate the fixup decision (p4-p1 >= M => true min
    // provably within {c1,c2,c3} => inline exact resolve).
    float b1[16], b2[16], b3[16], b4[16];
    const float FINF = __uint_as_float(0x7F800000u);
    #pragma unroll
    for (int s = 0; s < 16; ++s) { b1[s]=FINF; b2[s]=FINF; b3[s]=FINF; b4[s]=FINF; }

    // 24 MFMAs, j-outer / rg-inner; setprio(1) favors the matrix pipe while
    // the co-resident wave is in its VALU (KY) phase.
    auto MF = [&](f32x4* acc, const short8* B) {
        __builtin_amdgcn_s_setprio(1);
        #pragma unroll
        for (int rg = 0; rg < 4; ++rg) acc[rg] = f32x4{0.f, 0.f, 0.f, 0.f};
        #pragma unroll
        for (int rg = 0; rg < 4; ++rg)
            acc[rg] = __builtin_amdgcn_mfma_f32_16x16x32_bf16(Ah[rg][0], B[0], acc[rg], 0,0,0);
        #pragma unroll
        for (int rg = 0; rg < 4; ++rg)
            acc[rg] = __builtin_amdgcn_mfma_f32_16x16x32_bf16(Ah[rg][1], B[1], acc[rg], 0,0,0);
        #pragma unroll
        for (int rg = 0; rg < 4; ++rg)
            acc[rg] = __builtin_amdgcn_mfma_f32_16x16x32_bf16(Ah[rg][0], B[2], acc[rg], 0,0,0);
        #pragma unroll
        for (int rg = 0; rg < 4; ++rg)
            acc[rg] = __builtin_amdgcn_mfma_f32_16x16x32_bf16(Ah[rg][1], B[3], acc[rg], 0,0,0);
        #pragma unroll
        for (int rg = 0; rg < 4; ++rg)
            acc[rg] = __builtin_amdgcn_mfma_f32_16x16x32_bf16(Al[rg][0], B[0], acc[rg], 0,0,0);
        #pragma unroll
        for (int rg = 0; rg < 4; ++rg)
            acc[rg] = __builtin_amdgcn_mfma_f32_16x16x32_bf16(Al[rg][1], B[1], acc[rg], 0,0,0);
        __builtin_amdgcn_s_setprio(0);
    };

    // 16 key updates: fmaf + and_or + med3 x3 + min (sorted-4 insert)
    auto KY = [&](const f32x4* acc, float esqv, int ct) {
        const unsigned kcur = (unsigned)(ct*16 + res);
        #pragma unroll
        for (int rg = 0; rg < 4; ++rg) {
            #pragma unroll
            for (int r = 0; r < 4; ++r) {
                float v = fmaf(-2.0f, acc[rg][r], esqv);   // proxy = esq - 2*dot
                float key = __uint_as_float((__float_as_uint(v) & 0xFFFFFC00u) | kcur);
                const int s = rg*4 + r;
                float o1 = b1[s], o2 = b2[s], o3 = b3[s];
                b4[s] = __builtin_amdgcn_fmed3f(key, o3, b4[s]);
                b3[s] = __builtin_amdgcn_fmed3f(key, o2, o3);
                b2[s] = __builtin_amdgcn_fmed3f(key, o1, o2);
                b1[s] = fminf(o1, key);
            }
        }
    };

    f32x4 accA[4], accB[4];
    MF(accA, B0);                        // tile 0
    for (int p = 0; p < 15; ++p) {       // tiles 4p+1 .. 4p+4
        const int t = 4 * p;
        loadB(B0, t + 4);
        MF(accB, B1);                    // t+1
        KY(accA, e0, t);      e0 = esq[(t + 2) * 16 + res];
        loadB(B1, t + 5);
        MF(accA, B2);                    // t+2
        KY(accB, e1, t + 1);  e1 = esq[(t + 3) * 16 + res];
        loadB(B2, t + 6);
        MF(accB, B3);                    // t+3
        KY(accA, e0, t + 2);  e0 = esq[(t + 4) * 16 + res];
        loadB(B3, t + 7);
        MF(accA, B0);                    // t+4
        KY(accB, e1, t + 3);  e1 = esq[(t + 5) * 16 + res];
    }
    MF(accB, B1);                        // 61
    KY(accA, e0, 60);  e0 = esq[62 * 16 + res];
    MF(accA, B2);                        // 62
    KY(accB, e1, 61);  e1 = esq[63 * 16 + res];
    MF(accB, B3);                        // 63
    KY(accA, e0, 62);
    KY(accB, e1, 63);

    // top-4 merge across the 16 code-residue lanes (sorted-4 union network)
    #pragma unroll
    for (int m = 1; m < 16; m <<= 1) {
        #pragma unroll
        for (int s = 0; s < 16; ++s) {
            float oa1 = __shfl_xor(b1[s], m, 64);
            float oa2 = __shfl_xor(b2[s], m, 64);
            float oa3 = __shfl_xor(b3[s], m, 64);
            float oa4 = __shfl_xor(b4[s], m, 64);
            float m1 = fminf(b1[s], oa1);
            float m2 = fminf(fmaxf(b1[s], oa1), fminf(b2[s], oa2));
            float m3 = fminf(fminf(fmaxf(b1[s], oa2), fmaxf(b2[s], oa1)),
                             fminf(b3[s], oa3));
            float m4 = fminf(fminf(fmaxf(b1[s], oa3), fmaxf(b3[s], oa1)),
                             fminf(fmaxf(b2[s], oa2), fminf(b4[s], oa4)));
            b1[s] = m1; b2[s] = m2; b3[s] = m3; b4[s] = m4;
        }
    }

    __shared__ float s_k1[256], s_k2[256], s_k3[256], s_k4[256];
    __shared__ int s_idx[256];
    if (res == 0) {
        #pragma unroll
        for (int s = 0; s < 16; ++s) {   // row_local = w*64 + rg*16 + g*4 + r
            const int rl = w*64 + (s >> 2)*16 + g*4 + (s & 3);
            s_k1[rl] = b1[s]; s_k2[rl] = b2[s]; s_k3[rl] = b3[s]; s_k4[rl] = b4[s];
        }
    }
    __syncthreads();

    // resolve: outright winner / pair-exact / triple-exact / (rare) fixup
    {
        const int row = blockIdx.x * 256 + tid;
        unsigned u1 = __float_as_uint(s_k1[tid]);
        unsigned u2 = __float_as_uint(s_k2[tid]);
        unsigned u3 = __float_as_uint(s_k3[tid]);
        unsigned u4 = __float_as_uint(s_k4[tid]);
        float f1 = __uint_as_float(u1 & 0xFFFFFC00u);
        float f2 = __uint_as_float(u2 & 0xFFFFFC00u);
        float f3 = __uint_as_float(u3 & 0xFFFFFC00u);
        float f4 = __uint_as_float(u4 & 0xFFFFFC00u);
        int idx;
        if (f4 - f1 < MARGIN) {
            unsigned slot = atomicAdd(cnt, 1u);
            if (slot < LIST_CAP) list[slot] = (unsigned)row;
            idx = -1;                              // fixup owns this row
        } else if (f2 - f1 < MARGIN) {
            // np-exact resolve over 2 or 3 candidates (true min provably inside)
            const int nc = (f3 - f1 < MARGIN) ? 3 : 2;
            int cand[3] = {(int)(u1 & 0x3FFu), (int)(u2 & 0x3FFu), (int)(u3 & 0x3FFu)};
            float xv[DIM];
            const float4* xp = reinterpret_cast<const float4*>(x + (size_t)row * DIM);
            #pragma unroll
            for (int q = 0; q < 16; ++q) {
                float4 v = xp[q];
                xv[4*q+0] = v.x; xv[4*q+1] = v.y; xv[4*q+2] = v.z; xv[4*q+3] = v.w;
            }
            float xsq = np_sq64(xv);
            float bd = INFINITY; int bi = 0x7fffffff;
            for (int c = 0; c < nc; ++c) {
                const int k = cand[c];
                float tt = xsq + esq[k];
                float dd = tt - 2.0f * np_dot64(xv, emb + (size_t)k * DIM);
                if (dd < bd || (dd == bd && k < bi)) { bd = dd; bi = k; }
            }
            idx = bi;
        } else {
            idx = (int)(u1 & 0x3FFu);
        }
        s_idx[tid] = idx;
    }
    __syncthreads();

    // writeout: 2 threads per row (32 dims each), 2 passes (33 MB verified)
    float lsum = 0.f;
    #pragma unroll
    for (int pass = 0; pass < 2; ++pass) {
        const int rl = (tid >> 1) + pass * 128, half = tid & 1;
        const int row = blockIdx.x * 256 + rl;
        const int idx = s_idx[rl];
        if (idx >= 0) {
            const float* xr = x + (size_t)row * DIM + half*32;
            const float* qr = emb + (size_t)idx * DIM + half*32;
            float* orow = out + (size_t)row * DIM + half*32;
            #pragma unroll
            for (int i = 0; i < 8; ++i) {
                float4 xv = reinterpret_cast<const float4*>(xr)[i];
                float4 qv = reinterpret_cast<const float4*>(qr)[i];
                float df0 = qv.x - xv.x, df1 = qv.y - xv.y;
                float df2 = qv.z - xv.z, df3 = qv.w - xv.w;
                lsum = fmaf(df0, df0, lsum); lsum = fmaf(df1, df1, lsum);
                lsum = fmaf(df2, df2, lsum); lsum = fmaf(df3, df3, lsum);
                float4 o = {xv.x + df0, xv.y + df1, xv.z + df2, xv.w + df3};
                reinterpret_cast<float4*>(orow)[i] = o;
            }
            if (half == 0) out[(size_t)N_ROWS * DIM + row] = (float)idx;
        }
    }
    #pragma unroll
    for (int off = 32; off > 0; off >>= 1) lsum += __shfl_down(lsum, off, 64);
    if (lane == 0) atomicAdd(loss, lsum);
}

// full np-exact rescan, only for quad-tie rows (rare, ~1%)
__global__ void vq_fixup(const float* __restrict__ x, const float* __restrict__ emb,
                         const float* __restrict__ esq,
                         const unsigned int* __restrict__ cnt,
                         const unsigned int* __restrict__ list,
                         float* __restrict__ out, float* __restrict__ loss) {
#pragma clang fp contract(off)
    const int lane = threadIdx.x & 63;
    const int wid = (blockIdx.x * blockDim.x + threadIdx.x) >> 6;
    const int nw = (256 * 256) >> 6;
    unsigned count = *cnt;
    if (count > LIST_CAP) count = LIST_CAP;
    for (unsigned i = wid; i < count; i += nw) {
        const int row = (int)list[i];
        float xv[DIM];
        const float4* xp = reinterpret_cast<const float4*>(x + (size_t)row * DIM);
        #pragma unroll
        for (int q = 0; q < 16; ++q) {
            float4 v = xp[q];
            xv[4*q+0] = v.x; xv[4*q+1] = v.y; xv[4*q+2] = v.z; xv[4*q+3] = v.w;
        }
        float xsq = np_sq64(xv);
        float best = INFINITY; int bidx = 0x7fffffff;
        for (int t = 0; t < K_CODES / 64; ++t) {
            const int k = lane + t * 64;   // ascending per lane
            float dot = np_dot64(xv, emb + (size_t)k * DIM);
            float tt = xsq + esq[k];
            float dist = tt - 2.0f * dot;
            if (dist < best) { best = dist; bidx = k; }
        }
        #pragma unroll
        for (int m = 1; m < 64; m <<= 1) {   // lexicographic (dist, idx) min
            float ob = __shfl_xor(best, m, 64);
            int   oi = __shfl_xor(bidx, m, 64);
            if (ob < best || (ob == best && oi < bidx)) { best = ob; bidx = oi; }
        }
        const float xd = x[(size_t)row * DIM + lane];
        const float qd = emb[(size_t)bidx * DIM + lane];
        const float df = qd - xd;
        out[(size_t)row * DIM + lane] = xd + df;
        if (lane == 0) out[(size_t)N_ROWS * DIM + row] = (float)bidx;
        float l2 = df * df;
        #pragma unroll
        for (int off = 32; off > 0; off >>= 1) l2 += __shfl_down(l2, off, 64);
        if (lane == 0) atomicAdd(loss, l2);
    }
}

__global__ void vq_final(const float* __restrict__ loss_acc, float* __restrict__ out_loss) {
    if (threadIdx.x == 0 && blockIdx.x == 0)
        out_loss[0] = loss_acc[0] / (float)((size_t)N_ROWS * DIM);
}

extern "C" void kernel_launch(void* const* d_in, const int* in_sizes, int n_in,
                              void* d_out, int out_size, void* d_ws, size_t ws_size,
                              hipStream_t stream) {
    const float* x   = (const float*)d_in[0];
    const float* emb = (const float*)d_in[1];
    float* out = (float*)d_out;

    unsigned int* cnt  = (unsigned int*)d_ws;
    float* loss        = (float*)d_ws + 1;
    float* esq         = (float*)d_ws + 4;
    unsigned short* wsB = (unsigned short*)((char*)d_ws + 8192);
    unsigned int* list = (unsigned int*)((char*)d_ws + 270336);

    vq_prep<<<dim3(64), dim3(64), 0, stream>>>(emb, esq, wsB, cnt, loss);
    vq_mfma<<<dim3(N_ROWS / 256), dim3(256), 0, stream>>>(x, emb, esq, wsB, out,
                                                          cnt, list, loss);
    vq_fixup<<<dim3(256), dim3(256), 0, stream>>>(x, emb, esq, cnt, list, out, loss);
    vq_final<<<dim3(1), dim3(1), 0, stream>>>(loss, out + (size_t)N_ROWS * DIM + N_ROWS);
}